// Round 17
// baseline (433.999 us; speedup 1.0000x reference)
//
#include <hip/hip_runtime.h>
#include <hip/hip_fp16.h>
#include <stdint.h>

#define N_PRO 60000
#define N_WAT 40000
#define NN    100000
#define NNP   100032            // padded to a multiple of 64 for tiles
#define NE    1000000
#define IN_DIM 21
#define HID    32
#define HEADS  4
#define HC     128
#define EDGE_K 32
#define NSEG   ((NN + 1023) / 1024)
#define LUTN   2048             // distance-LUT bins, bin = dist*256 (range [0,8))
#define NH0B   ((NNP * 32) / 256)      // h0 blocks
#define NCNTB  ((NE + 255) / 256)      // degree-count blocks
#define NLUTB  ((2 * LUTN) / 256)      // LUT blocks (16)

typedef _Float16 half8 __attribute__((ext_vector_type(8)));
typedef float    f32x4 __attribute__((ext_vector_type(4)));

// ---------------------------------------------------------------------------
// K_PREP: one dispatch fusing four independent roles (block ranges):
//   [0, NH0B)            : h0 = feats@Wf+bf (fp16) + layer-1 logits asd
//   [NH0B, NH0B+NCNTB)   : edge degree count (atomicAdd deg)
//   [NH0B+NCNTB, +NLUTB) : distance LUT (per-block redundant U/aeb compute)
// The tiny folded weights (vas/vad/U/aeb/h0w) are recomputed per block that
// needs them (~8k FMA) instead of a separate k_small dispatch.
// ---------------------------------------------------------------------------
__global__ __launch_bounds__(256) void k_prep(
    const float* __restrict__ pf, const float* __restrict__ Wf,
    const float* __restrict__ bfv,
    const int* __restrict__ ei, int* __restrict__ deg,
    const float* __restrict__ We, const float* __restrict__ be,
    const float* __restrict__ Wedge1, const float* __restrict__ atte1,
    const float* __restrict__ Wedge2, const float* __restrict__ atte2,
    const float* __restrict__ W1, const float* __restrict__ atts1,
    const float* __restrict__ attd1, const float* __restrict__ gamma,
    __half* __restrict__ h0, float* __restrict__ asd,
    float* __restrict__ lut)
{
    int t = threadIdx.x;
    int bid = blockIdx.x;
    if (bid >= NH0B + NCNTB) {
        // ---- LUT role ----
        __shared__ float V[128];
        __shared__ float U[128];
        __shared__ float aeb[4];
        int lb = bid - (NH0B + NCNTB);          // 0..15
        int layer = lb >> 3;                    // 8 blocks per layer
        const float* Wg = layer ? Wedge2 : Wedge1;
        const float* ae = layer ? atte2 : atte1;
        if (t < 128) {
            int d = t >> 2, h = t & 3;
            float s = 0.f;
            for (int c = 0; c < HID; c++)
                s += Wg[d * HC + h * HID + c] * ae[h * HID + c];
            V[t] = s;
        }
        __syncthreads();
        if (t < 128) {
            int k = t >> 2, h = t & 3;
            float s = 0.f;
            for (int d = 0; d < 32; d++)
                s += We[k * 32 + d] * V[d * 4 + h];
            U[t] = s;
        } else if (t < 132) {
            int h = t - 128;
            float s = 0.f;
            for (int d = 0; d < 32; d++)
                s += be[d] * V[d * 4 + h];
            aeb[h] = s;
        }
        __syncthreads();
        int bin = (lb & 7) * 256 + t;
        float dd = bin * (1.0f / 256.0f);
        float g = gamma[0];
        float a0 = aeb[0], a1 = aeb[1], a2 = aeb[2], a3 = aeb[3];
        const float step = 5.0f / 31.0f;
        #pragma unroll
        for (int k = 0; k < EDGE_K; k++) {
            float tt = dd - (float)k * step;
            float r = __expf(-g * tt * tt);
            a0 += r * U[k * 4 + 0];
            a1 += r * U[k * 4 + 1];
            a2 += r * U[k * 4 + 2];
            a3 += r * U[k * 4 + 3];
        }
        *(float4*)&lut[((size_t)layer * LUTN + bin) * 4] =
            make_float4(a0, a1, a2, a3);
        return;
    }
    if (bid >= NH0B) {
        // ---- degree-count role ----
        int e = (bid - NH0B) * 256 + t;
        if (e < NE) {
            int d = ei[NE + e];
            int s = ei[e];
            if ((unsigned)d < (unsigned)NN && (unsigned)s < (unsigned)NN)
                atomicAdd(&deg[d], 1);
        }
        return;
    }
    // ---- h0 role ----
    __shared__ float Wfs[IN_DIM * 32];
    __shared__ float bfs[32];
    __shared__ float h0w[32];
    __shared__ float vas[128], vad[128];
    for (int i = t; i < IN_DIM * 32; i += 256) Wfs[i] = Wf[i];
    if (t < 32) { bfs[t] = bfv[t]; h0w[t] = Wf[20 * 32 + t] + bfv[t]; }
    {
        int side = t >> 7;
        int idx = t & 127;
        int h = idx >> 5, c = idx & 31;
        const float* av = side ? attd1 : atts1;
        float s = 0.f;
        for (int j = 0; j < 32; j++)
            s += W1[c * 128 + h * 32 + j] * av[h * 32 + j];
        (side ? vad : vas)[idx] = s;
    }
    __syncthreads();
    int id = bid * 256 + t;
    int n = id >> 5, c = id & 31;
    if (n >= NNP) return;
    float v;
    if (n < N_PRO) {
        float s = bfs[c];
        for (int k = 0; k < IN_DIM; k++)
            s += pf[n * IN_DIM + k] * Wfs[k * 32 + c];
        v = s;
    } else {
        v = h0w[c];
    }
    h0[(size_t)n * 32 + c] = __float2half(v);
    float ps[4], pd[4];
    #pragma unroll
    for (int h = 0; h < 4; h++) {
        ps[h] = v * vas[h * 32 + c];
        pd[h] = v * vad[h * 32 + c];
    }
    #pragma unroll
    for (int m = 1; m < 32; m <<= 1) {
        #pragma unroll
        for (int h = 0; h < 4; h++) {
            ps[h] += __shfl_xor(ps[h], m, 64);
            pd[h] += __shfl_xor(pd[h], m, 64);
        }
    }
    if ((t & 31) == 0) {
        *(float4*)&asd[(size_t)n * 8]     = make_float4(ps[0], ps[1], ps[2], ps[3]);
        *(float4*)&asd[(size_t)n * 8 + 4] = make_float4(pd[0], pd[1], pd[2], pd[3]);
    }
}

// ---------------------------------------------------------------------------
// CSR scan, 2 passes. off/cur stay SEGMENT-LOCAL; consumers add poff[seg].
// scan2 also emits off[NN] (= total - poff[97]) and wbound = global off[N_PRO].
// ---------------------------------------------------------------------------
__global__ __launch_bounds__(256) void k_scan1(
    const int* __restrict__ deg, int* __restrict__ off,
    int* __restrict__ cur, int* __restrict__ part)
{
    __shared__ int s[256];
    int t = threadIdx.x;
    int base = blockIdx.x * 1024 + t * 4;
    int d0 = 0, d1 = 0, d2 = 0, d3 = 0;
    if (base + 3 < NN) {
        int4 v = *(const int4*)&deg[base];
        d0 = v.x; d1 = v.y; d2 = v.z; d3 = v.w;
    } else {
        if (base + 0 < NN) d0 = deg[base + 0];
        if (base + 1 < NN) d1 = deg[base + 1];
        if (base + 2 < NN) d2 = deg[base + 2];
    }
    int tsum = d0 + d1 + d2 + d3;
    s[t] = tsum;
    __syncthreads();
    #pragma unroll
    for (int o = 1; o < 256; o <<= 1) {
        int v = (t >= o) ? s[t - o] : 0;
        __syncthreads();
        s[t] += v;
        __syncthreads();
    }
    int ex = s[t] - tsum;
    if (base + 0 < NN) { int v = ex;                 off[base + 0] = v; cur[base + 0] = v; }
    if (base + 1 < NN) { int v = ex + d0;            off[base + 1] = v; cur[base + 1] = v; }
    if (base + 2 < NN) { int v = ex + d0 + d1;       off[base + 2] = v; cur[base + 2] = v; }
    if (base + 3 < NN) { int v = ex + d0 + d1 + d2;  off[base + 3] = v; cur[base + 3] = v; }
    if (t == 255) part[blockIdx.x] = s[255];
}

__global__ __launch_bounds__(128) void k_scan2(
    const int* __restrict__ part, int* __restrict__ partoff,
    int* __restrict__ off, int* __restrict__ wbound)
{
    __shared__ int s[128];
    __shared__ int po[128];
    int t = threadIdx.x;
    int v = (t < NSEG) ? part[t] : 0;
    s[t] = v;
    __syncthreads();
    #pragma unroll
    for (int o = 1; o < 128; o <<= 1) {
        int x = (t >= o) ? s[t - o] : 0;
        __syncthreads();
        s[t] += x;
        __syncthreads();
    }
    po[t] = s[t] - v;   // exclusive segment prefix
    partoff[t] = po[t];
    __syncthreads();
    if (t == 0) {
        // G(NN) must equal total: off[NN] + po[NN>>10] == s[127]
        off[NN] = s[127] - po[NN >> 10];
        // water boundary in global coordinates
        wbound[0] = off[N_PRO] + po[N_PRO >> 10];
    }
}

// fill CSR: ONE packed 4B record per slot: (src << 15) | dist_code.
// Plain store (nt-hint measured WORSE in r16). Slot = local cur + segment base.
__global__ __launch_bounds__(256) void k_fill(
    const int* __restrict__ ei, int* __restrict__ cur,
    const int* __restrict__ poff, unsigned* __restrict__ e4,
    const float* __restrict__ ppos, const float* __restrict__ wpos)
{
    int e = blockIdx.x * 256 + threadIdx.x;
    if (e >= NE) return;
    int d = ei[NE + e];
    int s = ei[e];
    if ((unsigned)d >= (unsigned)NN || (unsigned)s >= (unsigned)NN) return;
    const float* ps = (s < N_PRO) ? &ppos[s * 3] : &wpos[(s - N_PRO) * 3];
    const float* pd = (d < N_PRO) ? &ppos[d * 3] : &wpos[(d - N_PRO) * 3];
    float dx = pd[0] - ps[0];
    float dy = pd[1] - ps[1];
    float dz = pd[2] - ps[2];
    float dd = sqrtf(dx * dx + dy * dy + dz * dz);
    unsigned code = (unsigned)fminf(dd * 4096.0f, 32767.0f);
    int p = atomicAdd(&cur[d], 1) + poff[d >> 10];
    e4[p] = ((unsigned)s << 15) | code;
}

// ---------------------------------------------------------------------------
// K6 (MFMA): x = hbuf @ W2 (+ logits) via mfma_f32_16x16x32_f16.
// ---------------------------------------------------------------------------
__global__ __launch_bounds__(256) void k_xm(
    const __half* __restrict__ h, const float* __restrict__ Wg,
    const float* __restrict__ atts, const float* __restrict__ attd,
    __half* __restrict__ x16, float* __restrict__ asd)
{
    __shared__ __half Wt[128 * 136];
    __shared__ float attS[128], attD[128];
    int t = threadIdx.x;
    for (int i = t; i < 128 * 32; i += 256) {
        int c = i & 127, d = (i >> 7) * 4;
        float w0 = Wg[(d + 0) * 128 + c];
        float w1 = Wg[(d + 1) * 128 + c];
        float w2 = Wg[(d + 2) * 128 + c];
        float w3 = Wg[(d + 3) * 128 + c];
        __half2 p0 = __floats2half2_rn(w0, w1);
        __half2 p1 = __floats2half2_rn(w2, w3);
        uint2 pk;
        pk.x = *(unsigned*)&p0;
        pk.y = *(unsigned*)&p1;
        *(uint2*)&Wt[c * 136 + d] = pk;
    }
    if (t < 128) { attS[t] = atts[t]; attD[t] = attd[t]; }
    __syncthreads();
    int wv = t >> 6, lane = t & 63;
    int m16 = lane & 15, quad = lane >> 4;
    int n0 = blockIdx.x * 64 + wv * 16;
    f32x4 acc[8];
    #pragma unroll
    for (int ct = 0; ct < 8; ct++) acc[ct] = (f32x4){0.f, 0.f, 0.f, 0.f};
    #pragma unroll
    for (int ks = 0; ks < 4; ks++) {
        int d0 = ks * 32 + quad * 8;
        half8 bf = *(const half8*)&h[(size_t)(n0 + m16) * 128 + d0];
        #pragma unroll
        for (int ct = 0; ct < 8; ct++) {
            half8 af = *(const half8*)&Wt[(ct * 16 + m16) * 136 + d0];
            acc[ct] = __builtin_amdgcn_mfma_f32_16x16x32_f16(af, bf, acc[ct], 0, 0, 0);
        }
    }
    __half* xrow = &x16[(size_t)(n0 + m16) * 128 + quad * 4];
    float ps[4] = {0.f, 0.f, 0.f, 0.f}, pd[4] = {0.f, 0.f, 0.f, 0.f};
    #pragma unroll
    for (int ct = 0; ct < 8; ct++) {
        f32x4 a = acc[ct];
        __half2 h0p = __floats2half2_rn(a[0], a[1]);
        __half2 h1p = __floats2half2_rn(a[2], a[3]);
        uint2 pk;
        pk.x = *(unsigned*)&h0p;
        pk.y = *(unsigned*)&h1p;
        *(uint2*)&xrow[ct * 16] = pk;
        int cb = ct * 16 + quad * 4;
        int hh = ct >> 1;
        ps[hh] += a[0] * attS[cb] + a[1] * attS[cb + 1]
                + a[2] * attS[cb + 2] + a[3] * attS[cb + 3];
        pd[hh] += a[0] * attD[cb] + a[1] * attD[cb + 1]
                + a[2] * attD[cb + 2] + a[3] * attD[cb + 3];
    }
    #pragma unroll
    for (int hh = 0; hh < 4; hh++) {
        ps[hh] += __shfl_xor(ps[hh], 16, 64);
        ps[hh] += __shfl_xor(ps[hh], 32, 64);
        pd[hh] += __shfl_xor(pd[hh], 16, 64);
        pd[hh] += __shfl_xor(pd[hh], 32, 64);
    }
    if (lane < 16) {
        int n = n0 + m16;
        *(float4*)&asd[(size_t)n * 8]     = make_float4(ps[0], ps[1], ps[2], ps[3]);
        *(float4*)&asd[(size_t)n * 8 + 4] = make_float4(pd[0], pd[1], pd[2], pd[3]);
    }
}

// ---------------------------------------------------------------------------
// K7 (partial logits, streaming): aP[i][4] = asd_src[src] + lut_lerp(dist).
// LAYER==2 skips slots below wbound[0] (protein dst).
// ---------------------------------------------------------------------------
template <int LAYER>
__global__ __launch_bounds__(256) void k_alphaP(
    const unsigned* __restrict__ e4, const int* __restrict__ wbound,
    const float* __restrict__ lutg, const float* __restrict__ asd,
    float* __restrict__ aP)
{
    int i = blockIdx.x * 256 + threadIdx.x;
    if (i >= NE) return;
    if (LAYER == 2 && i < wbound[0]) return;
    unsigned v = e4[i];
    int s = v >> 15;
    float f = fminf((v & 32767u) * 0.0625f, (float)(LUTN - 2));
    int i0 = (int)f;
    float fr = f - (float)i0;
    float4 A = *(const float4*)&lutg[(size_t)i0 * 4];
    float4 B = *(const float4*)&lutg[(size_t)(i0 + 1) * 4];
    float4 as4 = *(const float4*)&asd[(size_t)s * 8];
    float v0 = as4.x + A.x + (B.x - A.x) * fr;
    float v1 = as4.y + A.y + (B.y - A.y) * fr;
    float v2 = as4.z + A.z + (B.z - A.z) * fr;
    float v3 = as4.w + A.w + (B.w - A.w) * fr;
    *(float4*)&aP[(size_t)i * 4] = make_float4(v0, v1, v2, v3);
}

// ---------------------------------------------------------------------------
// K8a: layer-1 softmax-aggregation of RAW h0 into z[N,4,32] fp16. Lean loop;
// beg/end = segment-local off + poff base.
// ---------------------------------------------------------------------------
__global__ __launch_bounds__(256) void k_aggz(
    const int* __restrict__ off, const int* __restrict__ poff,
    const unsigned* __restrict__ e4,
    const float* __restrict__ aP, const float* __restrict__ asd,
    const __half* __restrict__ h016, __half* __restrict__ zbuf)
{
    int t = threadIdx.x;
    int w = t >> 6, lane = t & 63;
    int n = blockIdx.x * 4 + w;
    if (n >= NN) return;
    int h = lane >> 4, k16 = lane & 15;
    int beg = off[n] + poff[n >> 10];
    int end = off[n + 1] + poff[(n + 1) >> 10];
    float ad = asd[(size_t)n * 8 + 4 + h];
    const __half2* x2 = (const __half2*)h016;
    float lsum0 = 0.f, lsum1 = 0.f;
    float a00 = 0.f, a01 = 0.f, a10 = 0.f, a11 = 0.f;
    int i = beg;
    for (; i + 3 < end; i += 4) {
        unsigned s0 = e4[i] >> 15, s1 = e4[i + 1] >> 15;
        unsigned s2 = e4[i + 2] >> 15, s3 = e4[i + 3] >> 15;
        float v0 = aP[(unsigned)i * 4u + h] + ad;
        float v1 = aP[(unsigned)(i + 1) * 4u + h] + ad;
        float v2 = aP[(unsigned)(i + 2) * 4u + h] + ad;
        float v3 = aP[(unsigned)(i + 3) * 4u + h] + ad;
        float2 xv0 = __half22float2(x2[s0 * 16u + k16]);
        float2 xv1 = __half22float2(x2[s1 * 16u + k16]);
        float2 xv2 = __half22float2(x2[s2 * 16u + k16]);
        float2 xv3 = __half22float2(x2[s3 * 16u + k16]);
        v0 = fmaxf(v0, 0.2f * v0);
        v1 = fmaxf(v1, 0.2f * v1);
        v2 = fmaxf(v2, 0.2f * v2);
        v3 = fmaxf(v3, 0.2f * v3);
        float e0 = __expf(v0), e1 = __expf(v1);
        float e2v = __expf(v2), e3 = __expf(v3);
        lsum0 += e0 + e2v; lsum1 += e1 + e3;
        a00 += e0 * xv0.x + e2v * xv2.x;
        a01 += e0 * xv0.y + e2v * xv2.y;
        a10 += e1 * xv1.x + e3 * xv3.x;
        a11 += e1 * xv1.y + e3 * xv3.y;
    }
    for (; i < end; i++) {
        unsigned s0 = e4[i] >> 15;
        float v0 = aP[(unsigned)i * 4u + h] + ad;
        float2 xv0 = __half22float2(x2[s0 * 16u + k16]);
        v0 = fmaxf(v0, 0.2f * v0);
        float e0 = __expf(v0);
        lsum0 += e0;
        a00 += e0 * xv0.x; a01 += e0 * xv0.y;
    }
    float inv = 1.0f / (lsum0 + lsum1 + 1e-16f);
    *(__half2*)&zbuf[(size_t)n * 128 + lane * 2] =
        __floats2half2_rn((a00 + a10) * inv, (a01 + a11) * inv);
}

// ---------------------------------------------------------------------------
// K8a2 (k_zm, MFMA): hbuf = elu(z @blockdiag(W1) + b1).
// ---------------------------------------------------------------------------
__global__ __launch_bounds__(256) void k_zm(
    const __half* __restrict__ zbuf, const float* __restrict__ W1g,
    const float* __restrict__ b1, __half* __restrict__ hbuf)
{
    __shared__ __half Wt[128 * 40];   // [col c][k], 80B rows (16B aligned)
    int t = threadIdx.x;
    for (int i = t; i < 128 * 8; i += 256) {
        int c = i & 127, k4 = (i >> 7) * 4;
        float w0 = W1g[(k4 + 0) * 128 + c];
        float w1 = W1g[(k4 + 1) * 128 + c];
        float w2 = W1g[(k4 + 2) * 128 + c];
        float w3 = W1g[(k4 + 3) * 128 + c];
        __half2 p0 = __floats2half2_rn(w0, w1);
        __half2 p1 = __floats2half2_rn(w2, w3);
        uint2 pk;
        pk.x = *(unsigned*)&p0;
        pk.y = *(unsigned*)&p1;
        *(uint2*)&Wt[c * 40 + k4] = pk;
    }
    __syncthreads();
    int wv = t >> 6, lane = t & 63;
    int m16 = lane & 15, quad = lane >> 4;
    int n0 = blockIdx.x * 64 + wv * 16;
    half8 bf[4];
    #pragma unroll
    for (int hh = 0; hh < 4; hh++)
        bf[hh] = *(const half8*)&zbuf[(size_t)(n0 + m16) * 128 + hh * 32 + quad * 8];
    f32x4 acc[8];
    #pragma unroll
    for (int ct = 0; ct < 8; ct++) {
        half8 af = *(const half8*)&Wt[(ct * 16 + m16) * 40 + quad * 8];
        acc[ct] = __builtin_amdgcn_mfma_f32_16x16x32_f16(
            af, bf[ct >> 1], (f32x4){0.f, 0.f, 0.f, 0.f}, 0, 0, 0);
    }
    __half* orow = &hbuf[(size_t)(n0 + m16) * 128 + quad * 4];
    #pragma unroll
    for (int ct = 0; ct < 8; ct++) {
        int cb = ct * 16 + quad * 4;
        float4 bb = *(const float4*)&b1[cb];
        float r0 = acc[ct][0] + bb.x;
        float r1 = acc[ct][1] + bb.y;
        float r2 = acc[ct][2] + bb.z;
        float r3 = acc[ct][3] + bb.w;
        r0 = r0 > 0.f ? r0 : __expf(r0) - 1.0f;
        r1 = r1 > 0.f ? r1 : __expf(r1) - 1.0f;
        r2 = r2 > 0.f ? r2 : __expf(r2) - 1.0f;
        r3 = r3 > 0.f ? r3 : __expf(r3) - 1.0f;
        __half2 ha = __floats2half2_rn(r0, r1);
        __half2 hb = __floats2half2_rn(r2, r3);
        uint2 pk;
        pk.x = *(unsigned*)&ha;
        pk.y = *(unsigned*)&hb;
        *(uint2*)&orow[ct * 16] = pk;
    }
}

// ---------------------------------------------------------------------------
// K8b: layer-2 aggregation over pre-GEMMed x16 (water dst only).
// ---------------------------------------------------------------------------
__global__ __launch_bounds__(256) void k_agg2(
    const int* __restrict__ off, const int* __restrict__ poff,
    const unsigned* __restrict__ e4,
    const float* __restrict__ aP, const float* __restrict__ asd,
    const __half* __restrict__ x16, const float* __restrict__ bias,
    __half* __restrict__ hout)
{
    int t = threadIdx.x;
    int w = t >> 6, lane = t & 63;
    int n = N_PRO + blockIdx.x * 4 + w;
    if (n >= NN) return;
    int h = lane >> 4;
    int beg = off[n] + poff[n >> 10];
    int end = off[n + 1] + poff[(n + 1) >> 10];
    float ad = asd[(size_t)n * 8 + 4 + h];
    const __half2* x2 = (const __half2*)x16;
    float lsum0 = 0.f, lsum1 = 0.f;
    float a00 = 0.f, a01 = 0.f, a10 = 0.f, a11 = 0.f;
    int i = beg;
    for (; i + 3 < end; i += 4) {
        unsigned s0 = e4[i] >> 15, s1 = e4[i + 1] >> 15;
        unsigned s2 = e4[i + 2] >> 15, s3 = e4[i + 3] >> 15;
        float v0 = aP[(unsigned)i * 4u + h] + ad;
        float v1 = aP[(unsigned)(i + 1) * 4u + h] + ad;
        float v2 = aP[(unsigned)(i + 2) * 4u + h] + ad;
        float v3 = aP[(unsigned)(i + 3) * 4u + h] + ad;
        float2 xv0 = __half22float2(x2[s0 * 64u + lane]);
        float2 xv1 = __half22float2(x2[s1 * 64u + lane]);
        float2 xv2 = __half22float2(x2[s2 * 64u + lane]);
        float2 xv3 = __half22float2(x2[s3 * 64u + lane]);
        v0 = fmaxf(v0, 0.2f * v0);
        v1 = fmaxf(v1, 0.2f * v1);
        v2 = fmaxf(v2, 0.2f * v2);
        v3 = fmaxf(v3, 0.2f * v3);
        float e0 = __expf(v0), e1 = __expf(v1);
        float e2v = __expf(v2), e3 = __expf(v3);
        lsum0 += e0 + e2v; lsum1 += e1 + e3;
        a00 += e0 * xv0.x + e2v * xv2.x;
        a01 += e0 * xv0.y + e2v * xv2.y;
        a10 += e1 * xv1.x + e3 * xv3.x;
        a11 += e1 * xv1.y + e3 * xv3.y;
    }
    for (; i < end; i++) {
        unsigned s0 = e4[i] >> 15;
        float v0 = aP[(unsigned)i * 4u + h] + ad;
        float2 xv0 = __half22float2(x2[s0 * 64u + lane]);
        v0 = fmaxf(v0, 0.2f * v0);
        float e0 = __expf(v0);
        lsum0 += e0;
        a00 += e0 * xv0.x; a01 += e0 * xv0.y;
    }
    float lsum = lsum0 + lsum1;
    float acc0 = a00 + a10, acc1 = a01 + a11;
    float inv = 1.0f / (lsum + 1e-16f);
    float2 bbv = *(const float2*)&bias[lane * 2];
    float o0 = acc0 * inv + bbv.x;
    float o1 = acc1 * inv + bbv.y;
    o0 = o0 > 0.f ? o0 : __expf(o0) - 1.0f;
    o1 = o1 > 0.f ? o1 : __expf(o1) - 1.0f;
    *(__half2*)&hout[(size_t)n * 128 + lane * 2] = __floats2half2_rn(o0, o1);
}

// ---------------------------------------------------------------------------
// K9: water MLP. 32-node tile/block, padded stride 132, register-blocked.
// ---------------------------------------------------------------------------
__global__ __launch_bounds__(256) void k_mlp(
    const __half* __restrict__ hh, const float* __restrict__ Wm1,
    const float* __restrict__ bm1, const float* __restrict__ Wm2,
    const float* __restrict__ bm2, float* __restrict__ out)
{
    __shared__ float W1s[128 * 64];
    __shared__ float hs[32 * 132];
    int t = threadIdx.x;
    int g = t >> 5, q = t & 31;
    float b1r[2][2], w2r[2][2][2];
    #pragma unroll
    for (int hf = 0; hf < 2; hf++)
        #pragma unroll
        for (int j = 0; j < 2; j++) {
            int c = hf * 64 + q * 2 + j;
            b1r[hf][j] = bm1[c];
            w2r[hf][j][0] = Wm2[c * 2 + 0];
            w2r[hf][j][1] = Wm2[c * 2 + 1];
        }
    float b20 = bm2[0], b21 = bm2[1];
    int tile = blockIdx.x;
    {
        int r = t >> 3, c0 = (t & 7) * 16;
        const __half* src = &hh[(size_t)(N_PRO + tile * 32 + r) * 128 + c0];
        uint4 raw0 = *(const uint4*)src;
        uint4 raw1 = *(const uint4*)(src + 8);
        const __half2* hp0 = (const __half2*)&raw0;
        const __half2* hp1 = (const __half2*)&raw1;
        #pragma unroll
        for (int j = 0; j < 4; j++) {
            float2 fa = __half22float2(j < 2 ? hp0[2 * j] : hp1[2 * (j - 2)]);
            float2 fb = __half22float2(j < 2 ? hp0[2 * j + 1] : hp1[2 * (j - 2) + 1]);
            *(float4*)&hs[r * 132 + c0 + 4 * j] = make_float4(fa.x, fa.y, fb.x, fb.y);
        }
    }
    float p0[4] = {0.f, 0.f, 0.f, 0.f}, p1[4] = {0.f, 0.f, 0.f, 0.f};
    #pragma unroll
    for (int hf = 0; hf < 2; hf++) {
        __syncthreads();
        for (int i = t; i < 128 * 64; i += 256)
            W1s[i] = Wm1[(size_t)(i >> 6) * 128 + hf * 64 + (i & 63)];
        __syncthreads();
        float a[4][2];
        #pragma unroll
        for (int i = 0; i < 4; i++) { a[i][0] = 0.f; a[i][1] = 0.f; }
        for (int d0 = 0; d0 < 128; d0 += 4) {
            float4 hv[4];
            #pragma unroll
            for (int i = 0; i < 4; i++)
                hv[i] = *(const float4*)&hs[(g + 8 * i) * 132 + d0];
            #pragma unroll
            for (int dd = 0; dd < 4; dd++) {
                float2 wv = *(const float2*)&W1s[(d0 + dd) * 64 + q * 2];
                #pragma unroll
                for (int i = 0; i < 4; i++) {
                    float hvv = (&hv[i].x)[dd];
                    a[i][0] += hvv * wv.x;
                    a[i][1] += hvv * wv.y;
                }
            }
        }
        #pragma unroll
        for (int i = 0; i < 4; i++) {
            float a0 = fmaxf(a[i][0] + b1r[hf][0], 0.f);
            float a1 = fmaxf(a[i][1] + b1r[hf][1], 0.f);
            p0[i] += a0 * w2r[hf][0][0] + a1 * w2r[hf][1][0];
            p1[i] += a0 * w2r[hf][0][1] + a1 * w2r[hf][1][1];
        }
    }
    #pragma unroll
    for (int m = 1; m < 32; m <<= 1) {
        #pragma unroll
        for (int i = 0; i < 4; i++) {
            p0[i] += __shfl_xor(p0[i], m, 64);
            p1[i] += __shfl_xor(p1[i], m, 64);
        }
    }
    if (q == 0) {
        #pragma unroll
        for (int i = 0; i < 4; i++) {
            int n = tile * 32 + g + 8 * i;
            *(float2*)&out[n * 2] = make_float2(p0[i] + b20, p1[i] + b21);
        }
    }
}

// ---------------------------------------------------------------------------
extern "C" void kernel_launch(void* const* d_in, const int* in_sizes, int n_in,
                              void* d_out, int out_size, void* d_ws, size_t ws_size,
                              hipStream_t stream)
{
    const float* ppos   = (const float*)d_in[0];
    const float* wpos   = (const float*)d_in[1];
    const float* pfeat  = (const float*)d_in[2];
    const int*   ei     = (const int*)d_in[3];
    const float* gamma  = (const float*)d_in[4];
    const float* Wf     = (const float*)d_in[5];
    const float* bfv    = (const float*)d_in[6];
    const float* We     = (const float*)d_in[7];
    const float* be     = (const float*)d_in[8];
    const float* W1     = (const float*)d_in[9];
    const float* atts1  = (const float*)d_in[10];
    const float* attd1  = (const float*)d_in[11];
    const float* Wedge1 = (const float*)d_in[12];
    const float* atte1  = (const float*)d_in[13];
    const float* b1     = (const float*)d_in[14];
    const float* W2     = (const float*)d_in[15];
    const float* atts2  = (const float*)d_in[16];
    const float* attd2  = (const float*)d_in[17];
    const float* Wedge2 = (const float*)d_in[18];
    const float* atte2  = (const float*)d_in[19];
    const float* b2     = (const float*)d_in[20];
    const float* Wm1    = (const float*)d_in[21];
    const float* bm1    = (const float*)d_in[22];
    const float* Wm2    = (const float*)d_in[23];
    const float* bm2    = (const float*)d_in[24];
    float* out = (float*)d_out;

    char* ws = (char*)d_ws;
    size_t o = 0;
    auto alloc = [&](size_t bytes) -> char* {
        char* p = ws + o;
        o += (bytes + 255) & ~(size_t)255;
        return p;
    };
    __half*   h0      = (__half*)alloc((size_t)NNP * 32 * 2);
    __half*   x16     = (__half*)alloc((size_t)NNP * 128 * 2);   // also zbuf
    __half*   hbuf    = (__half*)alloc((size_t)NNP * 128 * 2);
    float*    asd     = (float*)alloc((size_t)NNP * 8 * 4);
    float*    aP      = (float*)alloc((size_t)NE * 4 * 4);
    int*      deg     = (int*)alloc((size_t)(NN + 1) * 4);
    int*      offp    = (int*)alloc((size_t)(NN + 1) * 4);
    int*      cur     = (int*)alloc((size_t)NN * 4);
    unsigned* e4      = (unsigned*)alloc((size_t)NE * 4);
    int*      part    = (int*)alloc((size_t)NSEG * 4);
    int*      partoff = (int*)alloc((size_t)(128 + 1) * 4);
    int*      wbound  = (int*)alloc(256);
    float*    lutbuf  = (float*)alloc((size_t)2 * LUTN * 4 * 4);

    hipMemsetAsync(deg, 0, (NN + 1) * 4, stream);
    // fused: h0 + logits, degree count, LUT (weights recomputed per block)
    k_prep<<<NH0B + NCNTB + NLUTB, 256, 0, stream>>>(
        pfeat, Wf, bfv, ei, deg, We, be, Wedge1, atte1, Wedge2, atte2,
        W1, atts1, attd1, gamma, h0, asd, lutbuf);
    k_scan1<<<NSEG, 256, 0, stream>>>(deg, offp, cur, part);
    k_scan2<<<1, 128, 0, stream>>>(part, partoff, offp, wbound);
    k_fill<<<(NE + 255) / 256, 256, 0, stream>>>(ei, cur, partoff, e4, ppos, wpos);
    // layer 1: partial logits (streaming) then lean aggregation, MFMA W1
    k_alphaP<1><<<(NE + 255) / 256, 256, 0, stream>>>(e4, wbound, lutbuf, asd, aP);
    k_aggz<<<NN / 4, 256, 0, stream>>>(offp, partoff, e4, aP, asd, h0, x16);
    k_zm<<<NNP / 64, 256, 0, stream>>>(x16, W1, b1, hbuf);
    // layer 2 (water destinations only)
    k_xm<<<NNP / 64, 256, 0, stream>>>(hbuf, W2, atts2, attd2, x16, asd);
    k_alphaP<2><<<(NE + 255) / 256, 256, 0, stream>>>(e4, wbound, lutbuf + (size_t)LUTN * 4, asd, aP);
    k_agg2<<<N_WAT / 4, 256, 0, stream>>>(offp, partoff, e4, aP, asd, x16, b2, hbuf);
    // MLP on water nodes
    k_mlp<<<N_WAT / 32, 256, 0, stream>>>(hbuf, Wm1, bm1, Wm2, bm2, out);
}

// Round 18
// 403.001 us; speedup vs baseline: 1.0769x; 1.0769x over previous
//
#include <hip/hip_runtime.h>
#include <hip/hip_fp16.h>
#include <stdint.h>

#define N_PRO 60000
#define N_WAT 40000
#define NN    100000
#define NNP   100032            // padded to a multiple of 64 for tiles
#define NE    1000000
#define IN_DIM 21
#define HID    32
#define HEADS  4
#define HC     128
#define EDGE_K 32
#define NSEG   ((NN + 1023) / 1024)
#define LUTN   2048             // distance-LUT bins, bin = dist*256 (range [0,8))
#define NH0B   ((NNP * 32) / 256)      // h0 blocks
#define NCNTB  ((NE + 255) / 256)      // degree-count blocks (fused into k_h0)

typedef _Float16 half8 __attribute__((ext_vector_type(8)));
typedef float    f32x4 __attribute__((ext_vector_type(4)));

// ---------------------------------------------------------------------------
// K1: tiny fused weights (ONE block — r17 showed per-block recompute is a
// regression). smallw floats: [0..127]=U1, [128..131]=aeb1, [132..259]=U2,
// [260..263]=aeb2, [264..295]=h0w, [296..423]=va_s1, [424..551]=va_d1
// ---------------------------------------------------------------------------
__global__ __launch_bounds__(256) void k_small(
    const float* We, const float* be,
    const float* Wedge1, const float* atte1,
    const float* Wedge2, const float* atte2,
    const float* Wf, const float* bfv,
    const float* W1, const float* atts1, const float* attd1,
    float* smallw)
{
    __shared__ float V[2][128];
    int t = threadIdx.x;
    {
        int l = t >> 7, dh = t & 127, d = dh >> 2, h = dh & 3;
        const float* Wg = l ? Wedge2 : Wedge1;
        const float* ae = l ? atte2 : atte1;
        float s = 0.f;
        for (int c = 0; c < HID; c++)
            s += Wg[d * HC + h * HID + c] * ae[h * HID + c];
        V[l][dh] = s;
    }
    __syncthreads();
    {
        int l = t >> 7, kh = t & 127, k = kh >> 2, h = kh & 3;
        float s = 0.f;
        for (int d = 0; d < 32; d++)
            s += We[k * 32 + d] * V[l][d * 4 + h];
        smallw[(l ? 132 : 0) + kh] = s;
    }
    if (t < 8) {
        int l = t >> 2, h = t & 3;
        float s = 0.f;
        for (int d = 0; d < 32; d++)
            s += be[d] * V[l][d * 4 + h];
        smallw[(l ? 260 : 128) + h] = s;
    }
    if (t >= 32 && t < 64) {
        int c = t - 32;
        smallw[264 + c] = Wf[20 * 32 + c] + bfv[c];
    }
    {
        int side = t >> 7;
        int h = (t >> 5) & 3, c = t & 31;
        const float* av = side ? attd1 : atts1;
        float s = 0.f;
        for (int j = 0; j < 32; j++)
            s += W1[c * 128 + h * 32 + j] * av[h * 32 + j];
        smallw[(side ? 424 : 296) + (t & 127)] = s;
    }
}

// ---------------------------------------------------------------------------
// K1b: distance LUT. bin b corresponds to dist = b/256.
// ---------------------------------------------------------------------------
__global__ __launch_bounds__(256) void k_lut(
    const float* __restrict__ smallw, const float* __restrict__ gamma,
    float* __restrict__ lut)
{
    int e = blockIdx.x * 256 + threadIdx.x;
    if (e >= 2 * LUTN) return;
    int layer = e >> 11, bin = e & (LUTN - 1);
    const float* U = smallw + (layer ? 132 : 0);
    const float* aeb = smallw + (layer ? 260 : 128);
    float dd = bin * (1.0f / 256.0f);
    float g = gamma[0];
    float a0 = aeb[0], a1 = aeb[1], a2 = aeb[2], a3 = aeb[3];
    const float step = 5.0f / 31.0f;
    #pragma unroll
    for (int k = 0; k < EDGE_K; k++) {
        float tt = dd - (float)k * step;
        float r = __expf(-g * tt * tt);
        a0 += r * U[k * 4 + 0];
        a1 += r * U[k * 4 + 1];
        a2 += r * U[k * 4 + 2];
        a3 += r * U[k * 4 + 3];
    }
    *(float4*)&lut[(size_t)e * 4] = make_float4(a0, a1, a2, a3);
}

// ---------------------------------------------------------------------------
// K2 (+ fused degree count, as in the r15 baseline): blocks < NH0B compute
// h0 = feats@Wf+bf (fp16) + layer-1 logits asd (reading precomputed smallw);
// blocks >= NH0B run the edge degree count.
// ---------------------------------------------------------------------------
__global__ __launch_bounds__(256) void k_h0(
    const float* __restrict__ pf, const float* __restrict__ Wf,
    const float* __restrict__ bfv, const float* __restrict__ smallw,
    const int* __restrict__ ei, int* __restrict__ deg,
    __half* __restrict__ h0, float* __restrict__ asd)
{
    int t = threadIdx.x;
    if (blockIdx.x >= NH0B) {
        int e = (blockIdx.x - NH0B) * 256 + t;
        if (e < NE) {
            int d = ei[NE + e];
            int s = ei[e];
            if ((unsigned)d < (unsigned)NN && (unsigned)s < (unsigned)NN)
                atomicAdd(&deg[d], 1);
        }
        return;
    }
    __shared__ float Wfs[IN_DIM * 32];
    __shared__ float bfs[32];
    __shared__ float h0w[32];
    __shared__ float vas[128], vad[128];
    for (int i = t; i < IN_DIM * 32; i += 256) Wfs[i] = Wf[i];
    if (t < 32) { bfs[t] = bfv[t]; h0w[t] = smallw[264 + t]; }
    if (t < 128) vas[t] = smallw[296 + t];
    else         vad[t - 128] = smallw[424 + (t - 128)];
    __syncthreads();
    int id = blockIdx.x * 256 + t;
    int n = id >> 5, c = id & 31;
    if (n >= NNP) return;
    float v;
    if (n < N_PRO) {
        float s = bfs[c];
        for (int k = 0; k < IN_DIM; k++)
            s += pf[n * IN_DIM + k] * Wfs[k * 32 + c];
        v = s;
    } else {
        v = h0w[c];
    }
    h0[(size_t)n * 32 + c] = __float2half(v);
    float ps[4], pd[4];
    #pragma unroll
    for (int h = 0; h < 4; h++) {
        ps[h] = v * vas[h * 32 + c];
        pd[h] = v * vad[h * 32 + c];
    }
    #pragma unroll
    for (int m = 1; m < 32; m <<= 1) {
        #pragma unroll
        for (int h = 0; h < 4; h++) {
            ps[h] += __shfl_xor(ps[h], m, 64);
            pd[h] += __shfl_xor(pd[h], m, 64);
        }
    }
    if ((t & 31) == 0) {
        *(float4*)&asd[(size_t)n * 8]     = make_float4(ps[0], ps[1], ps[2], ps[3]);
        *(float4*)&asd[(size_t)n * 8 + 4] = make_float4(pd[0], pd[1], pd[2], pd[3]);
    }
}

// ---------------------------------------------------------------------------
// CSR scan, 2 passes (scan3 deleted — verified correct in r17). off/cur stay
// SEGMENT-LOCAL; consumers add poff[seg]. scan2 emits off[NN] and wbound.
// ---------------------------------------------------------------------------
__global__ __launch_bounds__(256) void k_scan1(
    const int* __restrict__ deg, int* __restrict__ off,
    int* __restrict__ cur, int* __restrict__ part)
{
    __shared__ int s[256];
    int t = threadIdx.x;
    int base = blockIdx.x * 1024 + t * 4;
    int d0 = 0, d1 = 0, d2 = 0, d3 = 0;
    if (base + 3 < NN) {
        int4 v = *(const int4*)&deg[base];
        d0 = v.x; d1 = v.y; d2 = v.z; d3 = v.w;
    } else {
        if (base + 0 < NN) d0 = deg[base + 0];
        if (base + 1 < NN) d1 = deg[base + 1];
        if (base + 2 < NN) d2 = deg[base + 2];
    }
    int tsum = d0 + d1 + d2 + d3;
    s[t] = tsum;
    __syncthreads();
    #pragma unroll
    for (int o = 1; o < 256; o <<= 1) {
        int v = (t >= o) ? s[t - o] : 0;
        __syncthreads();
        s[t] += v;
        __syncthreads();
    }
    int ex = s[t] - tsum;
    if (base + 0 < NN) { int v = ex;                 off[base + 0] = v; cur[base + 0] = v; }
    if (base + 1 < NN) { int v = ex + d0;            off[base + 1] = v; cur[base + 1] = v; }
    if (base + 2 < NN) { int v = ex + d0 + d1;       off[base + 2] = v; cur[base + 2] = v; }
    if (base + 3 < NN) { int v = ex + d0 + d1 + d2;  off[base + 3] = v; cur[base + 3] = v; }
    if (t == 255) part[blockIdx.x] = s[255];
}

__global__ __launch_bounds__(128) void k_scan2(
    const int* __restrict__ part, int* __restrict__ partoff,
    int* __restrict__ off, int* __restrict__ wbound)
{
    __shared__ int s[128];
    __shared__ int po[128];
    int t = threadIdx.x;
    int v = (t < NSEG) ? part[t] : 0;
    s[t] = v;
    __syncthreads();
    #pragma unroll
    for (int o = 1; o < 128; o <<= 1) {
        int x = (t >= o) ? s[t - o] : 0;
        __syncthreads();
        s[t] += x;
        __syncthreads();
    }
    po[t] = s[t] - v;   // exclusive segment prefix
    partoff[t] = po[t];
    __syncthreads();
    if (t == 0) {
        off[NN] = s[127] - po[NN >> 10];            // G(NN) == total
        wbound[0] = off[N_PRO] + po[N_PRO >> 10];   // global water boundary
    }
}

// fill CSR: ONE packed 4B record per slot: (src << 15) | dist_code.
// Plain store (nt measured worse in r16). Slot = local cur + segment base.
__global__ __launch_bounds__(256) void k_fill(
    const int* __restrict__ ei, int* __restrict__ cur,
    const int* __restrict__ poff, unsigned* __restrict__ e4,
    const float* __restrict__ ppos, const float* __restrict__ wpos)
{
    int e = blockIdx.x * 256 + threadIdx.x;
    if (e >= NE) return;
    int d = ei[NE + e];
    int s = ei[e];
    if ((unsigned)d >= (unsigned)NN || (unsigned)s >= (unsigned)NN) return;
    const float* ps = (s < N_PRO) ? &ppos[s * 3] : &wpos[(s - N_PRO) * 3];
    const float* pd = (d < N_PRO) ? &ppos[d * 3] : &wpos[(d - N_PRO) * 3];
    float dx = pd[0] - ps[0];
    float dy = pd[1] - ps[1];
    float dz = pd[2] - ps[2];
    float dd = sqrtf(dx * dx + dy * dy + dz * dz);
    unsigned code = (unsigned)fminf(dd * 4096.0f, 32767.0f);
    int p = atomicAdd(&cur[d], 1) + poff[d >> 10];
    e4[p] = ((unsigned)s << 15) | code;
}

// ---------------------------------------------------------------------------
// K6 (MFMA): x = hbuf @ W2 (+ logits) via mfma_f32_16x16x32_f16.
// ---------------------------------------------------------------------------
__global__ __launch_bounds__(256) void k_xm(
    const __half* __restrict__ h, const float* __restrict__ Wg,
    const float* __restrict__ atts, const float* __restrict__ attd,
    __half* __restrict__ x16, float* __restrict__ asd)
{
    __shared__ __half Wt[128 * 136];
    __shared__ float attS[128], attD[128];
    int t = threadIdx.x;
    for (int i = t; i < 128 * 32; i += 256) {
        int c = i & 127, d = (i >> 7) * 4;
        float w0 = Wg[(d + 0) * 128 + c];
        float w1 = Wg[(d + 1) * 128 + c];
        float w2 = Wg[(d + 2) * 128 + c];
        float w3 = Wg[(d + 3) * 128 + c];
        __half2 p0 = __floats2half2_rn(w0, w1);
        __half2 p1 = __floats2half2_rn(w2, w3);
        uint2 pk;
        pk.x = *(unsigned*)&p0;
        pk.y = *(unsigned*)&p1;
        *(uint2*)&Wt[c * 136 + d] = pk;
    }
    if (t < 128) { attS[t] = atts[t]; attD[t] = attd[t]; }
    __syncthreads();
    int wv = t >> 6, lane = t & 63;
    int m16 = lane & 15, quad = lane >> 4;
    int n0 = blockIdx.x * 64 + wv * 16;
    f32x4 acc[8];
    #pragma unroll
    for (int ct = 0; ct < 8; ct++) acc[ct] = (f32x4){0.f, 0.f, 0.f, 0.f};
    #pragma unroll
    for (int ks = 0; ks < 4; ks++) {
        int d0 = ks * 32 + quad * 8;
        half8 bf = *(const half8*)&h[(size_t)(n0 + m16) * 128 + d0];
        #pragma unroll
        for (int ct = 0; ct < 8; ct++) {
            half8 af = *(const half8*)&Wt[(ct * 16 + m16) * 136 + d0];
            acc[ct] = __builtin_amdgcn_mfma_f32_16x16x32_f16(af, bf, acc[ct], 0, 0, 0);
        }
    }
    __half* xrow = &x16[(size_t)(n0 + m16) * 128 + quad * 4];
    float ps[4] = {0.f, 0.f, 0.f, 0.f}, pd[4] = {0.f, 0.f, 0.f, 0.f};
    #pragma unroll
    for (int ct = 0; ct < 8; ct++) {
        f32x4 a = acc[ct];
        __half2 h0p = __floats2half2_rn(a[0], a[1]);
        __half2 h1p = __floats2half2_rn(a[2], a[3]);
        uint2 pk;
        pk.x = *(unsigned*)&h0p;
        pk.y = *(unsigned*)&h1p;
        *(uint2*)&xrow[ct * 16] = pk;
        int cb = ct * 16 + quad * 4;
        int hh = ct >> 1;
        ps[hh] += a[0] * attS[cb] + a[1] * attS[cb + 1]
                + a[2] * attS[cb + 2] + a[3] * attS[cb + 3];
        pd[hh] += a[0] * attD[cb] + a[1] * attD[cb + 1]
                + a[2] * attD[cb + 2] + a[3] * attD[cb + 3];
    }
    #pragma unroll
    for (int hh = 0; hh < 4; hh++) {
        ps[hh] += __shfl_xor(ps[hh], 16, 64);
        ps[hh] += __shfl_xor(ps[hh], 32, 64);
        pd[hh] += __shfl_xor(pd[hh], 16, 64);
        pd[hh] += __shfl_xor(pd[hh], 32, 64);
    }
    if (lane < 16) {
        int n = n0 + m16;
        *(float4*)&asd[(size_t)n * 8]     = make_float4(ps[0], ps[1], ps[2], ps[3]);
        *(float4*)&asd[(size_t)n * 8 + 4] = make_float4(pd[0], pd[1], pd[2], pd[3]);
    }
}

// ---------------------------------------------------------------------------
// K7 (partial logits, streaming): aP[i][4] = asd_src[src] + lut_lerp(dist).
// LAYER==2 skips slots below wbound[0] (protein dst).
// ---------------------------------------------------------------------------
template <int LAYER>
__global__ __launch_bounds__(256) void k_alphaP(
    const unsigned* __restrict__ e4, const int* __restrict__ wbound,
    const float* __restrict__ lutg, const float* __restrict__ asd,
    float* __restrict__ aP)
{
    int i = blockIdx.x * 256 + threadIdx.x;
    if (i >= NE) return;
    if (LAYER == 2 && i < wbound[0]) return;
    unsigned v = e4[i];
    int s = v >> 15;
    float f = fminf((v & 32767u) * 0.0625f, (float)(LUTN - 2));
    int i0 = (int)f;
    float fr = f - (float)i0;
    float4 A = *(const float4*)&lutg[(size_t)i0 * 4];
    float4 B = *(const float4*)&lutg[(size_t)(i0 + 1) * 4];
    float4 as4 = *(const float4*)&asd[(size_t)s * 8];
    float v0 = as4.x + A.x + (B.x - A.x) * fr;
    float v1 = as4.y + A.y + (B.y - A.y) * fr;
    float v2 = as4.z + A.z + (B.z - A.z) * fr;
    float v3 = as4.w + A.w + (B.w - A.w) * fr;
    *(float4*)&aP[(size_t)i * 4] = make_float4(v0, v1, v2, v3);
}

// ---------------------------------------------------------------------------
// K8a: layer-1 softmax-aggregation of RAW h0 into z[N,4,32] fp16. Lean loop;
// beg/end = segment-local off + poff base.
// ---------------------------------------------------------------------------
__global__ __launch_bounds__(256) void k_aggz(
    const int* __restrict__ off, const int* __restrict__ poff,
    const unsigned* __restrict__ e4,
    const float* __restrict__ aP, const float* __restrict__ asd,
    const __half* __restrict__ h016, __half* __restrict__ zbuf)
{
    int t = threadIdx.x;
    int w = t >> 6, lane = t & 63;
    int n = blockIdx.x * 4 + w;
    if (n >= NN) return;
    int h = lane >> 4, k16 = lane & 15;
    int beg = off[n] + poff[n >> 10];
    int end = off[n + 1] + poff[(n + 1) >> 10];
    float ad = asd[(size_t)n * 8 + 4 + h];
    const __half2* x2 = (const __half2*)h016;
    float lsum0 = 0.f, lsum1 = 0.f;
    float a00 = 0.f, a01 = 0.f, a10 = 0.f, a11 = 0.f;
    int i = beg;
    for (; i + 3 < end; i += 4) {
        unsigned s0 = e4[i] >> 15, s1 = e4[i + 1] >> 15;
        unsigned s2 = e4[i + 2] >> 15, s3 = e4[i + 3] >> 15;
        float v0 = aP[(unsigned)i * 4u + h] + ad;
        float v1 = aP[(unsigned)(i + 1) * 4u + h] + ad;
        float v2 = aP[(unsigned)(i + 2) * 4u + h] + ad;
        float v3 = aP[(unsigned)(i + 3) * 4u + h] + ad;
        float2 xv0 = __half22float2(x2[s0 * 16u + k16]);
        float2 xv1 = __half22float2(x2[s1 * 16u + k16]);
        float2 xv2 = __half22float2(x2[s2 * 16u + k16]);
        float2 xv3 = __half22float2(x2[s3 * 16u + k16]);
        v0 = fmaxf(v0, 0.2f * v0);
        v1 = fmaxf(v1, 0.2f * v1);
        v2 = fmaxf(v2, 0.2f * v2);
        v3 = fmaxf(v3, 0.2f * v3);
        float e0 = __expf(v0), e1 = __expf(v1);
        float e2v = __expf(v2), e3 = __expf(v3);
        lsum0 += e0 + e2v; lsum1 += e1 + e3;
        a00 += e0 * xv0.x + e2v * xv2.x;
        a01 += e0 * xv0.y + e2v * xv2.y;
        a10 += e1 * xv1.x + e3 * xv3.x;
        a11 += e1 * xv1.y + e3 * xv3.y;
    }
    for (; i < end; i++) {
        unsigned s0 = e4[i] >> 15;
        float v0 = aP[(unsigned)i * 4u + h] + ad;
        float2 xv0 = __half22float2(x2[s0 * 16u + k16]);
        v0 = fmaxf(v0, 0.2f * v0);
        float e0 = __expf(v0);
        lsum0 += e0;
        a00 += e0 * xv0.x; a01 += e0 * xv0.y;
    }
    float inv = 1.0f / (lsum0 + lsum1 + 1e-16f);
    *(__half2*)&zbuf[(size_t)n * 128 + lane * 2] =
        __floats2half2_rn((a00 + a10) * inv, (a01 + a11) * inv);
}

// ---------------------------------------------------------------------------
// K8a2 (k_zm, MFMA): hbuf = elu(z @blockdiag(W1) + b1).
// ---------------------------------------------------------------------------
__global__ __launch_bounds__(256) void k_zm(
    const __half* __restrict__ zbuf, const float* __restrict__ W1g,
    const float* __restrict__ b1, __half* __restrict__ hbuf)
{
    __shared__ __half Wt[128 * 40];   // [col c][k], 80B rows (16B aligned)
    int t = threadIdx.x;
    for (int i = t; i < 128 * 8; i += 256) {
        int c = i & 127, k4 = (i >> 7) * 4;
        float w0 = W1g[(k4 + 0) * 128 + c];
        float w1 = W1g[(k4 + 1) * 128 + c];
        float w2 = W1g[(k4 + 2) * 128 + c];
        float w3 = W1g[(k4 + 3) * 128 + c];
        __half2 p0 = __floats2half2_rn(w0, w1);
        __half2 p1 = __floats2half2_rn(w2, w3);
        uint2 pk;
        pk.x = *(unsigned*)&p0;
        pk.y = *(unsigned*)&p1;
        *(uint2*)&Wt[c * 40 + k4] = pk;
    }
    __syncthreads();
    int wv = t >> 6, lane = t & 63;
    int m16 = lane & 15, quad = lane >> 4;
    int n0 = blockIdx.x * 64 + wv * 16;
    half8 bf[4];
    #pragma unroll
    for (int hh = 0; hh < 4; hh++)
        bf[hh] = *(const half8*)&zbuf[(size_t)(n0 + m16) * 128 + hh * 32 + quad * 8];
    f32x4 acc[8];
    #pragma unroll
    for (int ct = 0; ct < 8; ct++) {
        half8 af = *(const half8*)&Wt[(ct * 16 + m16) * 40 + quad * 8];
        acc[ct] = __builtin_amdgcn_mfma_f32_16x16x32_f16(
            af, bf[ct >> 1], (f32x4){0.f, 0.f, 0.f, 0.f}, 0, 0, 0);
    }
    __half* orow = &hbuf[(size_t)(n0 + m16) * 128 + quad * 4];
    #pragma unroll
    for (int ct = 0; ct < 8; ct++) {
        int cb = ct * 16 + quad * 4;
        float4 bb = *(const float4*)&b1[cb];
        float r0 = acc[ct][0] + bb.x;
        float r1 = acc[ct][1] + bb.y;
        float r2 = acc[ct][2] + bb.z;
        float r3 = acc[ct][3] + bb.w;
        r0 = r0 > 0.f ? r0 : __expf(r0) - 1.0f;
        r1 = r1 > 0.f ? r1 : __expf(r1) - 1.0f;
        r2 = r2 > 0.f ? r2 : __expf(r2) - 1.0f;
        r3 = r3 > 0.f ? r3 : __expf(r3) - 1.0f;
        __half2 ha = __floats2half2_rn(r0, r1);
        __half2 hb = __floats2half2_rn(r2, r3);
        uint2 pk;
        pk.x = *(unsigned*)&ha;
        pk.y = *(unsigned*)&hb;
        *(uint2*)&orow[ct * 16] = pk;
    }
}

// ---------------------------------------------------------------------------
// K8b: layer-2 aggregation over pre-GEMMed x16 (water dst only).
// ---------------------------------------------------------------------------
__global__ __launch_bounds__(256) void k_agg2(
    const int* __restrict__ off, const int* __restrict__ poff,
    const unsigned* __restrict__ e4,
    const float* __restrict__ aP, const float* __restrict__ asd,
    const __half* __restrict__ x16, const float* __restrict__ bias,
    __half* __restrict__ hout)
{
    int t = threadIdx.x;
    int w = t >> 6, lane = t & 63;
    int n = N_PRO + blockIdx.x * 4 + w;
    if (n >= NN) return;
    int h = lane >> 4;
    int beg = off[n] + poff[n >> 10];
    int end = off[n + 1] + poff[(n + 1) >> 10];
    float ad = asd[(size_t)n * 8 + 4 + h];
    const __half2* x2 = (const __half2*)x16;
    float lsum0 = 0.f, lsum1 = 0.f;
    float a00 = 0.f, a01 = 0.f, a10 = 0.f, a11 = 0.f;
    int i = beg;
    for (; i + 3 < end; i += 4) {
        unsigned s0 = e4[i] >> 15, s1 = e4[i + 1] >> 15;
        unsigned s2 = e4[i + 2] >> 15, s3 = e4[i + 3] >> 15;
        float v0 = aP[(unsigned)i * 4u + h] + ad;
        float v1 = aP[(unsigned)(i + 1) * 4u + h] + ad;
        float v2 = aP[(unsigned)(i + 2) * 4u + h] + ad;
        float v3 = aP[(unsigned)(i + 3) * 4u + h] + ad;
        float2 xv0 = __half22float2(x2[s0 * 64u + lane]);
        float2 xv1 = __half22float2(x2[s1 * 64u + lane]);
        float2 xv2 = __half22float2(x2[s2 * 64u + lane]);
        float2 xv3 = __half22float2(x2[s3 * 64u + lane]);
        v0 = fmaxf(v0, 0.2f * v0);
        v1 = fmaxf(v1, 0.2f * v1);
        v2 = fmaxf(v2, 0.2f * v2);
        v3 = fmaxf(v3, 0.2f * v3);
        float e0 = __expf(v0), e1 = __expf(v1);
        float e2v = __expf(v2), e3 = __expf(v3);
        lsum0 += e0 + e2v; lsum1 += e1 + e3;
        a00 += e0 * xv0.x + e2v * xv2.x;
        a01 += e0 * xv0.y + e2v * xv2.y;
        a10 += e1 * xv1.x + e3 * xv3.x;
        a11 += e1 * xv1.y + e3 * xv3.y;
    }
    for (; i < end; i++) {
        unsigned s0 = e4[i] >> 15;
        float v0 = aP[(unsigned)i * 4u + h] + ad;
        float2 xv0 = __half22float2(x2[s0 * 64u + lane]);
        v0 = fmaxf(v0, 0.2f * v0);
        float e0 = __expf(v0);
        lsum0 += e0;
        a00 += e0 * xv0.x; a01 += e0 * xv0.y;
    }
    float lsum = lsum0 + lsum1;
    float acc0 = a00 + a10, acc1 = a01 + a11;
    float inv = 1.0f / (lsum + 1e-16f);
    float2 bbv = *(const float2*)&bias[lane * 2];
    float o0 = acc0 * inv + bbv.x;
    float o1 = acc1 * inv + bbv.y;
    o0 = o0 > 0.f ? o0 : __expf(o0) - 1.0f;
    o1 = o1 > 0.f ? o1 : __expf(o1) - 1.0f;
    *(__half2*)&hout[(size_t)n * 128 + lane * 2] = __floats2half2_rn(o0, o1);
}

// ---------------------------------------------------------------------------
// K9: water MLP. 32-node tile/block, padded stride 132, register-blocked.
// ---------------------------------------------------------------------------
__global__ __launch_bounds__(256) void k_mlp(
    const __half* __restrict__ hh, const float* __restrict__ Wm1,
    const float* __restrict__ bm1, const float* __restrict__ Wm2,
    const float* __restrict__ bm2, float* __restrict__ out)
{
    __shared__ float W1s[128 * 64];
    __shared__ float hs[32 * 132];
    int t = threadIdx.x;
    int g = t >> 5, q = t & 31;
    float b1r[2][2], w2r[2][2][2];
    #pragma unroll
    for (int hf = 0; hf < 2; hf++)
        #pragma unroll
        for (int j = 0; j < 2; j++) {
            int c = hf * 64 + q * 2 + j;
            b1r[hf][j] = bm1[c];
            w2r[hf][j][0] = Wm2[c * 2 + 0];
            w2r[hf][j][1] = Wm2[c * 2 + 1];
        }
    float b20 = bm2[0], b21 = bm2[1];
    int tile = blockIdx.x;
    {
        int r = t >> 3, c0 = (t & 7) * 16;
        const __half* src = &hh[(size_t)(N_PRO + tile * 32 + r) * 128 + c0];
        uint4 raw0 = *(const uint4*)src;
        uint4 raw1 = *(const uint4*)(src + 8);
        const __half2* hp0 = (const __half2*)&raw0;
        const __half2* hp1 = (const __half2*)&raw1;
        #pragma unroll
        for (int j = 0; j < 4; j++) {
            float2 fa = __half22float2(j < 2 ? hp0[2 * j] : hp1[2 * (j - 2)]);
            float2 fb = __half22float2(j < 2 ? hp0[2 * j + 1] : hp1[2 * (j - 2) + 1]);
            *(float4*)&hs[r * 132 + c0 + 4 * j] = make_float4(fa.x, fa.y, fb.x, fb.y);
        }
    }
    float p0[4] = {0.f, 0.f, 0.f, 0.f}, p1[4] = {0.f, 0.f, 0.f, 0.f};
    #pragma unroll
    for (int hf = 0; hf < 2; hf++) {
        __syncthreads();
        for (int i = t; i < 128 * 64; i += 256)
            W1s[i] = Wm1[(size_t)(i >> 6) * 128 + hf * 64 + (i & 63)];
        __syncthreads();
        float a[4][2];
        #pragma unroll
        for (int i = 0; i < 4; i++) { a[i][0] = 0.f; a[i][1] = 0.f; }
        for (int d0 = 0; d0 < 128; d0 += 4) {
            float4 hv[4];
            #pragma unroll
            for (int i = 0; i < 4; i++)
                hv[i] = *(const float4*)&hs[(g + 8 * i) * 132 + d0];
            #pragma unroll
            for (int dd = 0; dd < 4; dd++) {
                float2 wv = *(const float2*)&W1s[(d0 + dd) * 64 + q * 2];
                #pragma unroll
                for (int i = 0; i < 4; i++) {
                    float hvv = (&hv[i].x)[dd];
                    a[i][0] += hvv * wv.x;
                    a[i][1] += hvv * wv.y;
                }
            }
        }
        #pragma unroll
        for (int i = 0; i < 4; i++) {
            float a0 = fmaxf(a[i][0] + b1r[hf][0], 0.f);
            float a1 = fmaxf(a[i][1] + b1r[hf][1], 0.f);
            p0[i] += a0 * w2r[hf][0][0] + a1 * w2r[hf][1][0];
            p1[i] += a0 * w2r[hf][0][1] + a1 * w2r[hf][1][1];
        }
    }
    #pragma unroll
    for (int m = 1; m < 32; m <<= 1) {
        #pragma unroll
        for (int i = 0; i < 4; i++) {
            p0[i] += __shfl_xor(p0[i], m, 64);
            p1[i] += __shfl_xor(p1[i], m, 64);
        }
    }
    if (q == 0) {
        #pragma unroll
        for (int i = 0; i < 4; i++) {
            int n = tile * 32 + g + 8 * i;
            *(float2*)&out[n * 2] = make_float2(p0[i] + b20, p1[i] + b21);
        }
    }
}

// ---------------------------------------------------------------------------
extern "C" void kernel_launch(void* const* d_in, const int* in_sizes, int n_in,
                              void* d_out, int out_size, void* d_ws, size_t ws_size,
                              hipStream_t stream)
{
    const float* ppos   = (const float*)d_in[0];
    const float* wpos   = (const float*)d_in[1];
    const float* pfeat  = (const float*)d_in[2];
    const int*   ei     = (const int*)d_in[3];
    const float* gamma  = (const float*)d_in[4];
    const float* Wf     = (const float*)d_in[5];
    const float* bfv    = (const float*)d_in[6];
    const float* We     = (const float*)d_in[7];
    const float* be     = (const float*)d_in[8];
    const float* W1     = (const float*)d_in[9];
    const float* atts1  = (const float*)d_in[10];
    const float* attd1  = (const float*)d_in[11];
    const float* Wedge1 = (const float*)d_in[12];
    const float* atte1  = (const float*)d_in[13];
    const float* b1     = (const float*)d_in[14];
    const float* W2     = (const float*)d_in[15];
    const float* atts2  = (const float*)d_in[16];
    const float* attd2  = (const float*)d_in[17];
    const float* Wedge2 = (const float*)d_in[18];
    const float* atte2  = (const float*)d_in[19];
    const float* b2     = (const float*)d_in[20];
    const float* Wm1    = (const float*)d_in[21];
    const float* bm1    = (const float*)d_in[22];
    const float* Wm2    = (const float*)d_in[23];
    const float* bm2    = (const float*)d_in[24];
    float* out = (float*)d_out;

    char* ws = (char*)d_ws;
    size_t o = 0;
    auto alloc = [&](size_t bytes) -> char* {
        char* p = ws + o;
        o += (bytes + 255) & ~(size_t)255;
        return p;
    };
    __half*   h0      = (__half*)alloc((size_t)NNP * 32 * 2);
    __half*   x16     = (__half*)alloc((size_t)NNP * 128 * 2);   // also zbuf
    __half*   hbuf    = (__half*)alloc((size_t)NNP * 128 * 2);
    float*    asd     = (float*)alloc((size_t)NNP * 8 * 4);
    float*    aP      = (float*)alloc((size_t)NE * 4 * 4);
    int*      deg     = (int*)alloc((size_t)(NN + 1) * 4);
    int*      offp    = (int*)alloc((size_t)(NN + 1) * 4);
    int*      cur     = (int*)alloc((size_t)NN * 4);
    unsigned* e4      = (unsigned*)alloc((size_t)NE * 4);
    int*      part    = (int*)alloc((size_t)NSEG * 4);
    int*      partoff = (int*)alloc((size_t)(128 + 1) * 4);
    int*      wbound  = (int*)alloc(256);
    float*    smallw  = (float*)alloc(4096);
    float*    lutbuf  = (float*)alloc((size_t)2 * LUTN * 4 * 4);

    hipMemsetAsync(deg, 0, (NN + 1) * 4, stream);
    k_small<<<1, 256, 0, stream>>>(We, be, Wedge1, atte1, Wedge2, atte2, Wf, bfv,
                                   W1, atts1, attd1, smallw);
    k_lut<<<(2 * LUTN + 255) / 256, 256, 0, stream>>>(smallw, gamma, lutbuf);
    // h0 + fused degree count (r15 baseline structure)
    k_h0<<<NH0B + NCNTB, 256, 0, stream>>>(pfeat, Wf, bfv, smallw, ei, deg, h0, asd);
    k_scan1<<<NSEG, 256, 0, stream>>>(deg, offp, cur, part);
    k_scan2<<<1, 128, 0, stream>>>(part, partoff, offp, wbound);
    k_fill<<<(NE + 255) / 256, 256, 0, stream>>>(ei, cur, partoff, e4, ppos, wpos);
    // layer 1: partial logits (streaming) then lean aggregation, MFMA W1
    k_alphaP<1><<<(NE + 255) / 256, 256, 0, stream>>>(e4, wbound, lutbuf, asd, aP);
    k_aggz<<<NN / 4, 256, 0, stream>>>(offp, partoff, e4, aP, asd, h0, x16);
    k_zm<<<NNP / 64, 256, 0, stream>>>(x16, W1, b1, hbuf);
    // layer 2 (water destinations only)
    k_xm<<<NNP / 64, 256, 0, stream>>>(hbuf, W2, atts2, attd2, x16, asd);
    k_alphaP<2><<<(NE + 255) / 256, 256, 0, stream>>>(e4, wbound, lutbuf + (size_t)LUTN * 4, asd, aP);
    k_agg2<<<N_WAT / 4, 256, 0, stream>>>(offp, partoff, e4, aP, asd, x16, b2, hbuf);
    // MLP on water nodes
    k_mlp<<<N_WAT / 32, 256, 0, stream>>>(hbuf, Wm1, bm1, Wm2, bm2, out);
}